// Round 15
// baseline (297.139 us; speedup 1.0000x reference)
//
#include <hip/hip_runtime.h>
#include <math.h>

#define NEL 10
#define FD 64
#define NBES 8
#define GG 20
#define HML 16
#define EGB 512   // geom blocks (polpart rows)
#define NUB 5000  // node_update blocks = N/4

typedef __attribute__((ext_vector_type(8))) short short8;
typedef __attribute__((ext_vector_type(4))) float f32x4;

__device__ __forceinline__ float wred(float v) {
    #pragma unroll
    for (int off = 32; off > 0; off >>= 1) v += __shfl_down(v, off, 64);
    return v;
}

__device__ __forceinline__ float silu(float h) {
    return h / (1.f + __expf(-h));
}

__device__ __forceinline__ unsigned short f2bf(float x) {
    unsigned int b = __float_as_uint(x);
    unsigned int r = (b + 0x7FFFu + ((b >> 16) & 1u)) >> 16;
    return (unsigned short)r;
}

// Node init (ballot species, scal, E0, q, agg0 zero) + receiver histogram + out[0..G) zero.
__global__ __launch_bounds__(256) void setup_k(
    const float* __restrict__ attrs, const float* __restrict__ ae,
    const float* __restrict__ fc, const float* __restrict__ embed_w,
    const int* __restrict__ eidx, int* __restrict__ spec,
    float* __restrict__ q, float* __restrict__ out,
    float* __restrict__ scal, float* __restrict__ agg0,
    int* __restrict__ cnt, int N_, int E_)
{
    int idx = blockIdx.x * 256 + threadIdx.x;
    int lane = threadIdx.x & 63;
    int n = idx >> 6;
    bool pred = (lane < NEL) && (attrs[(size_t)n * NEL + lane] > 0.5f);
    unsigned long long m = __ballot(pred);
    int sp = (int)__builtin_ctzll(m);
    scal[idx] = embed_w[sp * FD + lane];
    agg0[idx] = 0.f;
    if (lane == 0) { spec[n] = sp; q[n] = fc[sp]; out[GG + n] = ae[sp]; }
    if (idx < E_) atomicAdd(&cnt[eidx[E_ + idx]], 1);
    if (idx < GG) out[idx] = 0.f;          // total-energy accumulators (atomicAdd targets)
}

// Single-block shuffle scan + W1/W2 -> bf16 fragment order.
__global__ __launch_bounds__(1024) void scan_k(
    const int* __restrict__ cnt, int* __restrict__ cur,
    const float* __restrict__ w1, const float* __restrict__ w2,
    unsigned short* __restrict__ w1bf, unsigned short* __restrict__ w2bf, int N_)
{
    int t = threadIdx.x;
    #pragma unroll
    for (int ii = 0; ii < 8; ++ii) {
        int idx = ii * 1024 + t;            // = l*4096 + f*64 + k
        int l = idx >> 12, rem = idx & 4095;
        int f = rem >> 6, k = rem & 63;
        w2bf[idx] = f2bf(w2[l * 4096 + k * 64 + f]);
    }
    {
        int l = t >> 9, rem = t & 511;
        int m = rem >> 3, j = rem & 7;
        w1bf[t] = f2bf(w1[l * 512 + j * 64 + m]);
    }
    __shared__ int wtot[16];
    int lane = t & 63, wid = t >> 6;
    int base = t * 20;
    int c[20]; int s = 0;
    #pragma unroll
    for (int i = 0; i < 20; ++i) { int idx = base + i; c[i] = (idx < N_) ? cnt[idx] : 0; s += c[i]; }
    int v = s;
    #pragma unroll
    for (int off = 1; off < 64; off <<= 1) {
        int u = __shfl_up(v, off, 64);
        if (lane >= off) v += u;
    }
    if (lane == 63) wtot[wid] = v;
    __syncthreads();
    if (wid == 0 && lane < 16) {
        int wv = wtot[lane];
        #pragma unroll
        for (int off = 1; off < 16; off <<= 1) {
            int u = __shfl_up(wv, off, 64);
            if (lane >= off) wv += u;
        }
        wtot[lane] = wv;
    }
    __syncthreads();
    int ex = (wid > 0 ? wtot[wid - 1] : 0) + (v - s);
    #pragma unroll
    for (int i = 0; i < 20; ++i) {
        int idx = base + i;
        if (idx < N_) { cur[idx] = ex; ex += c[i]; }
    }
}

// Fused scatter + edge geometry: bessel(bf16)/flux from original edge list,
// written directly at receiver-sorted slot. Pol partials per block.
__global__ __launch_bounds__(256) void geom_scatter_k(
    const float* __restrict__ pos, const int* __restrict__ eidx,
    const float* __restrict__ flux_w, int* __restrict__ cur,
    int* __restrict__ snd_s, int* __restrict__ rcv_s,
    unsigned short* __restrict__ ef_bf, float* __restrict__ polpart,
    int E_, int ng)
{
    __shared__ float lpol[GG * 3];
    int tid = threadIdx.x;
    for (int i = tid; i < GG * 3; i += 256) lpol[i] = 0.f;
    __syncthreads();
    float fw[NBES];
    #pragma unroll
    for (int i = 0; i < NBES; ++i) fw[i] = flux_w[i] + flux_w[NBES + i];
    const float PI = 3.14159265358979323846f;
    for (int e = blockIdx.x * 256 + tid; e < E_; e += EGB * 256) {
        int s = eidx[e], r = eidx[E_ + e];
        float dx = pos[(size_t)r*3+0] - pos[(size_t)s*3+0];
        float dy = pos[(size_t)r*3+1] - pos[(size_t)s*3+1];
        float dz = pos[(size_t)r*3+2] - pos[(size_t)s*3+2];
        float len = sqrtf(dx*dx + dy*dy + dz*dz + 1e-12f);
        float x = len * 0.2f;
        float u = 0.f;
        if (x < 1.f) {
            float x2 = x * x;
            float x5 = x2 * x2 * x;
            u = 1.f - 21.f * x5 + 35.f * x5 * x - 15.f * x5 * x2;
        }
        float pref = 0.6324555320336759f / len * u;
        float theta = PI * x;
        float s1, c1;
        __sincosf(theta, &s1, &c1);
        float c2 = 2.f * c1;
        float sp_ = 0.f, sn = s1;
        float flux = 0.f;
        unsigned int pk[4];
        #pragma unroll
        for (int i = 0; i < 4; ++i) {
            float r0 = pref * sn;
            float n1 = c2 * sn - sp_; sp_ = sn; sn = n1;
            float r1 = pref * sn;
            n1 = c2 * sn - sp_; sp_ = sn; sn = n1;
            flux += r0 * fw[2*i] + r1 * fw[2*i+1];
            pk[i] = (unsigned int)f2bf(r0) | ((unsigned int)f2bf(r1) << 16);
        }
        int p = atomicAdd(&cur[r], 1);
        *(uint4*)&ef_bf[(size_t)p * NBES] = make_uint4(pk[0], pk[1], pk[2], pk[3]);
        snd_s[p] = s;
        rcv_s[p] = r;
        int g = r / ng;
        atomicAdd(&lpol[g*3+0], flux * dx);
        atomicAdd(&lpol[g*3+1], flux * dy);
        atomicAdd(&lpol[g*3+2], flux * dz);
    }
    __syncthreads();
    for (int i = tid; i < GG * 3; i += 256) polpart[blockIdx.x * (GG * 3) + i] = lpol[i];
}

// Radial MLP (both phases MFMA) + segmented scatter. Each wave owns 32 ADJACENT
// sorted edges (2 tiles): weights/descriptors amortized, run carries across the
// tile boundary. Wave-private LDS, zero barriers; locality preserved (blockIdx
// = sorted order).
__global__ __launch_bounds__(256, 8) void edge_mlp_k(
    const unsigned short* __restrict__ ef_bf, const int* __restrict__ snd_s,
    const int* __restrict__ rcv_s,
    const unsigned short* __restrict__ w1bf, const float* __restrict__ b1,
    const unsigned short* __restrict__ w2bf, const float* __restrict__ scal,
    float* __restrict__ agg0, int layer, int E_)
{
    __shared__ __align__(16) char smem[4][4352];
    int t = threadIdx.x, w = t >> 6, lane = t & 63;
    int mrow = lane & 15, quad = lane >> 4;
    int base = blockIdx.x * 128 + w * 32;      // 32 consecutive sorted edges per wave
    unsigned short* hw = (unsigned short*)smem[w];
    float* cw = (float*)smem[w];

    // descriptors for all 32 positions in lanes 0..31
    int sv = 0, rv = 0;
    if (lane < 32) { sv = snd_s[base + lane]; rv = rcv_s[base + lane]; }

    const short8 z8 = {0,0,0,0,0,0,0,0};
    short8 b_ef0 = z8, b_ef1 = z8;
    if (quad == 0) {
        b_ef0 = *(const short8*)&ef_bf[(size_t)(base + mrow) * NBES];
        b_ef1 = *(const short8*)&ef_bf[(size_t)(base + 16 + mrow) * NBES];
    } else if (quad == 1) { b_ef0[0] = (short)0x3F80; b_ef1[0] = (short)0x3F80; }

    // weight preamble: once per wave, shared by both tiles
    short8 a1f[4];
    #pragma unroll
    for (int nt = 0; nt < 4; ++nt) {
        a1f[nt] = z8;
        if (quad == 0) a1f[nt] = *(const short8*)&w1bf[layer * 512 + (nt * 16 + mrow) * 8];
        else if (quad == 1) a1f[nt][0] = (short)f2bf(b1[layer * FD + nt * 16 + mrow]);
    }
    const unsigned short* wb = w2bf + layer * 4096;
    short8 bf0[4], bf1[4];
    #pragma unroll
    for (int nt = 0; nt < 4; ++nt) {
        bf0[nt] = *(const short8*)&wb[(nt * 16 + mrow) * 64 + quad * 8];
        bf1[nt] = *(const short8*)&wb[(nt * 16 + mrow) * 64 + 32 + quad * 8];
    }

    f32x4 zf = {0.f, 0.f, 0.f, 0.f};
    int curR = __builtin_amdgcn_readlane(rv, 0);
    float run = 0.f;

    #pragma unroll
    for (int tile = 0; tile < 2; ++tile) {
        int pb = tile * 16;
        short8 b_ef = tile ? b_ef1 : b_ef0;

        // scal gathers for this tile (tile1's issue after tile0's epilogue;
        // latency hides under tile1's MFMA phases)
        float sw[16];
        #pragma unroll
        for (int pp = 0; pp < 16; ++pp) {
            int s = __builtin_amdgcn_readlane(sv, pb + pp);
            sw[pp] = scal[(size_t)s * FD + lane];
        }

        // phase 1: h^T = [W1^T|b1] @ [ef|1]^T  (4 MFMAs), silu, pack bf16 -> hw
        #pragma unroll
        for (int nt = 0; nt < 4; ++nt) {
            f32x4 c1 = __builtin_amdgcn_mfma_f32_16x16x32_bf16(a1f[nt], b_ef, zf, 0, 0, 0);
            unsigned int p01 = (unsigned int)f2bf(silu(c1[0])) | ((unsigned int)f2bf(silu(c1[1])) << 16);
            unsigned int p23 = (unsigned int)f2bf(silu(c1[2])) | ((unsigned int)f2bf(silu(c1[3])) << 16);
            *(uint2*)&hw[mrow * 72 + nt * 16 + quad * 4] = make_uint2(p01, p23);
        }

        // phase 2: A = h @ W2 (8 MFMAs)
        short8 a0  = *(const short8*)&hw[mrow * 72 + quad * 8];
        short8 a1b = *(const short8*)&hw[mrow * 72 + 32 + quad * 8];
        f32x4 c[4];
        #pragma unroll
        for (int nt = 0; nt < 4; ++nt) {
            f32x4 cc = __builtin_amdgcn_mfma_f32_16x16x32_bf16(a0, bf0[nt], zf, 0, 0, 0);
            cc = __builtin_amdgcn_mfma_f32_16x16x32_bf16(a1b, bf1[nt], cc, 0, 0, 0);
            c[nt] = cc;
        }
        #pragma unroll
        for (int nt = 0; nt < 4; ++nt)
            #pragma unroll
            for (int reg = 0; reg < 4; ++reg)
                cw[(quad * 4 + reg) * 68 + nt * 16 + mrow] = c[nt][reg];

        // epilogue: batched ctile reads, segmented reduce; run carries across tiles
        #pragma unroll
        for (int half = 0; half < 2; ++half) {
            float cv[8];
            #pragma unroll
            for (int k = 0; k < 8; ++k) cv[k] = cw[(half * 8 + k) * 68 + lane];
            #pragma unroll
            for (int k = 0; k < 8; ++k) {
                int pp = pb + half * 8 + k;
                int r = __builtin_amdgcn_readlane(rv, pp);
                float v = cv[k] * sw[half * 8 + k];
                if (r != curR) {
                    atomicAdd(&agg0[(size_t)curR * FD + lane], run);
                    run = v; curR = r;
                } else {
                    run += v;
                }
            }
        }
    }
    atomicAdd(&agg0[(size_t)curR * FD + lane], run);
}

// Node update + block-level energy partial (nEpart[layer][block]).
__global__ __launch_bounds__(256) void node_update_k(
    float* __restrict__ scal, float* __restrict__ agg0,
    const int* __restrict__ spec, const float* __restrict__ prod_w,
    const float* __restrict__ readout_w, const float* __restrict__ ro2_w1,
    const float* __restrict__ ro2_b1, const float* __restrict__ ro2_w2,
    const float* __restrict__ charge_w, float* __restrict__ q,
    float* __restrict__ out_nodeE, float* __restrict__ nEpart,
    int layer, int last, int N_)
{
    __shared__ float vsh[4][FD];
    __shared__ float red[4];
    int wid = threadIdx.x >> 6, lane = threadIdx.x & 63;
    int n = blockIdx.x * 4 + wid;
    int sp = spec[n];
    size_t idx = (size_t)n * FD + lane;
    float a = agg0[idx] * 0.0625f;
    agg0[idx] = 0.f;
    float v = a + a * a + scal[idx] * prod_w[(layer * NEL + sp) * FD + lane];
    scal[idx] = v;

    float ne;
    if (!last) {
        ne = wred(v * readout_w[layer * FD + lane]);
    } else {
        vsh[wid][lane] = v;                    // wave-private, in-order DS
        float h = 0.f;
        if (lane < HML) {
            h = ro2_b1[lane];
            for (int ff = 0; ff < FD; ++ff) h += vsh[wid][ff] * ro2_w1[ff * HML + lane];
            h = silu(h) * ro2_w2[lane];
        }
        ne = wred(h);
    }
    float qs = wred(v * charge_w[layer * FD + lane]);
    if (lane == 0) {
        out_nodeE[n] += ne;
        q[n] += qs;
        red[wid] = ne;
    }
    __syncthreads();
    if (threadIdx.x == 0) nEpart[layer * NUB + blockIdx.x] = red[0] + red[1] + red[2] + red[3];
}

// Coulomb via triangular 64x64 chunk pairs (136/graph) + 1 reduce block/graph.
__global__ __launch_bounds__(256) void coulomb_final_k(
    const float* __restrict__ q, const float* __restrict__ pos,
    const int* __restrict__ spec, const float* __restrict__ ae,
    const float* __restrict__ fc, const float* __restrict__ nEpart,
    const float* __restrict__ polpart, float* __restrict__ out,
    int N_, int ng)
{
    __shared__ float sh[260];
    int vb = blockIdx.x;
    int g = vb / 137, rem = vb % 137;
    int t = threadIdx.x, lane = t & 63, w = t >> 6;

    if (rem < 136) {
        int a = 0, r2 = rem;
        while (r2 >= 16 - a) { r2 -= 16 - a; ++a; }
        int b = a + r2;
        const float* qg = q + (size_t)g * ng;
        const float* pg = pos + (size_t)g * ng * 3;
        float* qs_ = sh; float* jx = sh + 64; float* jy = sh + 128; float* jz = sh + 192;
        if (t < 64) {
            int j = b * 64 + t;
            bool ok = j < ng;
            qs_[t] = ok ? qg[j] : 0.f;
            jx[t] = ok ? pg[(size_t)j*3+0] : 0.f;
            jy[t] = ok ? pg[(size_t)j*3+1] : 0.f;
            jz[t] = ok ? pg[(size_t)j*3+2] : 0.f;
        }
        __syncthreads();
        int i = a * 64 + lane;
        float accu = 0.f;
        if (i < ng) {
            float qi = qg[i];
            float xi = pg[(size_t)i*3+0], yi = pg[(size_t)i*3+1], zi = pg[(size_t)i*3+2];
            #pragma unroll 4
            for (int k = 0; k < 16; ++k) {
                int jj = w * 16 + k;                  // wave-uniform -> LDS broadcast
                int j = b * 64 + jj;
                float dx = xi - jx[jj], dy = yi - jy[jj], dz = zi - jz[jj];
                float d2 = dx*dx + dy*dy + dz*dz + 1e-12f;
                float rinv = __frsqrt_rn(d2);
                float r = d2 * rinv;
                float x = 0.5f * r;
                float tt = __frcp_rn(1.f + 0.3275911f * x);
                float poly = ((((1.061405429f*tt - 1.453152027f)*tt + 1.421413741f)*tt
                               - 0.284496736f)*tt + 0.254829592f)*tt;
                float erfv = 1.f - poly * __expf(-x * x);
                float kern = (j == i) ? 0.f : erfv * rinv;
                accu += qi * qs_[jj] * kern;
            }
        }
        accu = wred(accu);
        if (lane == 0) sh[256 + w] = accu;
        __syncthreads();
        if (t == 0) {
            float s = sh[256] + sh[257] + sh[258] + sh[259];
            atomicAdd(&out[g], (a == b) ? 0.5f * s : s);
        }
    } else {
        float se0 = 0.f, sq = 0.f, p0 = 0.f, p1 = 0.f, p2 = 0.f, s0 = 0.f, s1 = 0.f;
        for (int n = g * ng + t; n < (g + 1) * ng; n += 256) {
            int sp = spec[n];
            float fq = fc[sp];
            se0 += ae[sp];
            sq += q[n];
            p0 += fq * pos[(size_t)n*3+0];
            p1 += fq * pos[(size_t)n*3+1];
            p2 += fq * pos[(size_t)n*3+2];
        }
        if (t < 250) {
            int b = g * 250 + t;
            s0 = nEpart[b];
            s1 = nEpart[NUB + b];
        }
        for (int b = t; b < EGB; b += 256) {
            p0 += polpart[b * (GG * 3) + g * 3 + 0];
            p1 += polpart[b * (GG * 3) + g * 3 + 1];
            p2 += polpart[b * (GG * 3) + g * 3 + 2];
        }
        float vals[7] = {se0, s0, s1, sq, p0, p1, p2};
        float* red = sh;
        #pragma unroll
        for (int k = 0; k < 7; ++k) {
            float r = wred(vals[k]);
            if (lane == 0) red[w * 8 + k] = r;
        }
        __syncthreads();
        if (t < 7) sh[64 + t] = red[t] + red[8 + t] + red[16 + t] + red[24 + t];
        __syncthreads();
        if (t == 0) {
            float a0 = sh[64], a1 = sh[65], a2 = sh[66];
            atomicAdd(&out[g], a0 + a1 + a2);
            float* contrib = out + GG + N_;
            contrib[g*3+0] = a0; contrib[g*3+1] = a1; contrib[g*3+2] = a2;
            float* pol = contrib + GG * 3;
            pol[g*3+0] = sh[68]; pol[g*3+1] = sh[69]; pol[g*3+2] = sh[70];
            float* qt = pol + GG * 3;
            qt[g] = sh[67];
        }
    }
}

extern "C" void kernel_launch(void* const* d_in, const int* in_sizes, int n_in,
                              void* d_out, int out_size, void* d_ws, size_t ws_size,
                              hipStream_t stream)
{
    const float* node_attrs      = (const float*)d_in[0];
    const float* positions       = (const float*)d_in[1];
    const int*   edge_index      = (const int*)d_in[2];
    const float* atomic_energies = (const float*)d_in[5];
    const float* embed_w         = (const float*)d_in[6];
    const float* radial_w1       = (const float*)d_in[7];
    const float* radial_b1       = (const float*)d_in[8];
    const float* radial_w2       = (const float*)d_in[9];
    const float* prod_w          = (const float*)d_in[10];
    const float* readout_w       = (const float*)d_in[11];
    const float* ro2_w1          = (const float*)d_in[12];
    const float* ro2_b1          = (const float*)d_in[13];
    const float* ro2_w2          = (const float*)d_in[14];
    const float* charge_w        = (const float*)d_in[15];
    const float* flux_w          = (const float*)d_in[16];
    const float* formal_charges  = (const float*)d_in[17];

    int N = in_sizes[0] / NEL;     // 20000
    int E = in_sizes[2] / 2;       // 320000
    int ng = N / GG;               // 1000

    float* ws      = (float*)d_ws;
    float* scal    = ws;                                   // [N,64]
    float* agg0    = scal + (size_t)N * FD;                // [N,64]
    unsigned short* ef_bf = (unsigned short*)(agg0 + (size_t)N * FD); // [E,8] bf16 sorted
    float* q       = (float*)(ef_bf + (size_t)E * NBES);   // [N]
    int*   spec    = (int*)(q + N);                        // [N]
    float* nEpart  = (float*)(spec + N);                   // [2*NUB]
    float* polpart = nEpart + 2 * NUB;                     // [EGB*60]
    int*   cnt     = (int*)(polpart + EGB * (GG * 3));     // [N]  (memset)
    int*   cur     = cnt + N;                              // [N]
    int*   snd_s   = cur + N;                              // [E]
    int*   rcv_s   = snd_s + E;                            // [E]
    unsigned short* w2bf = (unsigned short*)(rcv_s + E);   // [2*4096]
    unsigned short* w1bf = w2bf + 8192;                    // [2*512]

    float* out = (float*)d_out;
    float* out_nodeE = out + GG;

    hipMemsetAsync(cnt, 0, (size_t)N * sizeof(int), stream);

    setup_k<<<(N * FD) / 256, 256, 0, stream>>>(
        node_attrs, atomic_energies, formal_charges, embed_w, edge_index,
        spec, q, out, scal, agg0, cnt, N, E);
    scan_k<<<1, 1024, 0, stream>>>(cnt, cur, radial_w1, radial_w2, w1bf, w2bf, N);
    geom_scatter_k<<<EGB, 256, 0, stream>>>(
        positions, edge_index, flux_w, cur, snd_s, rcv_s, ef_bf, polpart, E, ng);

    for (int l = 0; l < 2; ++l) {
        edge_mlp_k<<<E / 128, 256, 0, stream>>>(
            ef_bf, snd_s, rcv_s, w1bf, radial_b1, w2bf, scal, agg0, l, E);
        node_update_k<<<N / 4, 256, 0, stream>>>(
            scal, agg0, spec, prod_w, readout_w, ro2_w1, ro2_b1, ro2_w2,
            charge_w, q, out_nodeE, nEpart, l, (l == 1) ? 1 : 0, N);
    }

    coulomb_final_k<<<GG * 137, 256, 0, stream>>>(
        q, positions, spec, atomic_energies, formal_charges,
        nEpart, polpart, out, N, ng);
}

// Round 16
// 283.913 us; speedup vs baseline: 1.0466x; 1.0466x over previous
//
#include <hip/hip_runtime.h>
#include <math.h>

#define NEL 10
#define FD 64
#define NBES 8
#define GG 20
#define HML 16
#define EGB 512   // geom blocks (polpart rows)
#define NUB 5000  // node_update blocks = N/4

typedef __attribute__((ext_vector_type(8))) short short8;
typedef __attribute__((ext_vector_type(4))) float f32x4;

__device__ __forceinline__ float wred(float v) {
    #pragma unroll
    for (int off = 32; off > 0; off >>= 1) v += __shfl_down(v, off, 64);
    return v;
}

__device__ __forceinline__ float silu(float h) {
    return h / (1.f + __expf(-h));
}

__device__ __forceinline__ unsigned short f2bf(float x) {
    unsigned int b = __float_as_uint(x);
    unsigned int r = (b + 0x7FFFu + ((b >> 16) & 1u)) >> 16;
    return (unsigned short)r;
}

// Node init (ballot species, scal, E0, q, agg0 zero) + receiver histogram + out[0..G) zero.
__global__ __launch_bounds__(256) void setup_k(
    const float* __restrict__ attrs, const float* __restrict__ ae,
    const float* __restrict__ fc, const float* __restrict__ embed_w,
    const int* __restrict__ eidx, int* __restrict__ spec,
    float* __restrict__ q, float* __restrict__ out,
    float* __restrict__ scal, float* __restrict__ agg0,
    int* __restrict__ cnt, int N_, int E_)
{
    int idx = blockIdx.x * 256 + threadIdx.x;
    int lane = threadIdx.x & 63;
    int n = idx >> 6;
    bool pred = (lane < NEL) && (attrs[(size_t)n * NEL + lane] > 0.5f);
    unsigned long long m = __ballot(pred);
    int sp = (int)__builtin_ctzll(m);
    scal[idx] = embed_w[sp * FD + lane];
    agg0[idx] = 0.f;
    if (lane == 0) { spec[n] = sp; q[n] = fc[sp]; out[GG + n] = ae[sp]; }
    if (idx < E_) atomicAdd(&cnt[eidx[E_ + idx]], 1);
    if (idx < GG) out[idx] = 0.f;          // total-energy accumulators (atomicAdd targets)
}

// Single-block shuffle scan + W1/W2 -> bf16 fragment order.
__global__ __launch_bounds__(1024) void scan_k(
    const int* __restrict__ cnt, int* __restrict__ cur,
    const float* __restrict__ w1, const float* __restrict__ w2,
    unsigned short* __restrict__ w1bf, unsigned short* __restrict__ w2bf, int N_)
{
    int t = threadIdx.x;
    #pragma unroll
    for (int ii = 0; ii < 8; ++ii) {
        int idx = ii * 1024 + t;            // = l*4096 + f*64 + k
        int l = idx >> 12, rem = idx & 4095;
        int f = rem >> 6, k = rem & 63;
        w2bf[idx] = f2bf(w2[l * 4096 + k * 64 + f]);
    }
    {
        int l = t >> 9, rem = t & 511;
        int m = rem >> 3, j = rem & 7;
        w1bf[t] = f2bf(w1[l * 512 + j * 64 + m]);
    }
    __shared__ int wtot[16];
    int lane = t & 63, wid = t >> 6;
    int base = t * 20;
    int c[20]; int s = 0;
    #pragma unroll
    for (int i = 0; i < 20; ++i) { int idx = base + i; c[i] = (idx < N_) ? cnt[idx] : 0; s += c[i]; }
    int v = s;
    #pragma unroll
    for (int off = 1; off < 64; off <<= 1) {
        int u = __shfl_up(v, off, 64);
        if (lane >= off) v += u;
    }
    if (lane == 63) wtot[wid] = v;
    __syncthreads();
    if (wid == 0 && lane < 16) {
        int wv = wtot[lane];
        #pragma unroll
        for (int off = 1; off < 16; off <<= 1) {
            int u = __shfl_up(wv, off, 64);
            if (lane >= off) wv += u;
        }
        wtot[lane] = wv;
    }
    __syncthreads();
    int ex = (wid > 0 ? wtot[wid - 1] : 0) + (v - s);
    #pragma unroll
    for (int i = 0; i < 20; ++i) {
        int idx = base + i;
        if (idx < N_) { cur[idx] = ex; ex += c[i]; }
    }
}

// Fused scatter + edge geometry: bessel(bf16)/flux from original edge list,
// written directly at receiver-sorted slot. Pol partials per block.
__global__ __launch_bounds__(256) void geom_scatter_k(
    const float* __restrict__ pos, const int* __restrict__ eidx,
    const float* __restrict__ flux_w, int* __restrict__ cur,
    int* __restrict__ snd_s, int* __restrict__ rcv_s,
    unsigned short* __restrict__ ef_bf, float* __restrict__ polpart,
    int E_, int ng)
{
    __shared__ float lpol[GG * 3];
    int tid = threadIdx.x;
    for (int i = tid; i < GG * 3; i += 256) lpol[i] = 0.f;
    __syncthreads();
    float fw[NBES];
    #pragma unroll
    for (int i = 0; i < NBES; ++i) fw[i] = flux_w[i] + flux_w[NBES + i];
    const float PI = 3.14159265358979323846f;
    for (int e = blockIdx.x * 256 + tid; e < E_; e += EGB * 256) {
        int s = eidx[e], r = eidx[E_ + e];
        float dx = pos[(size_t)r*3+0] - pos[(size_t)s*3+0];
        float dy = pos[(size_t)r*3+1] - pos[(size_t)s*3+1];
        float dz = pos[(size_t)r*3+2] - pos[(size_t)s*3+2];
        float len = sqrtf(dx*dx + dy*dy + dz*dz + 1e-12f);
        float x = len * 0.2f;
        float u = 0.f;
        if (x < 1.f) {
            float x2 = x * x;
            float x5 = x2 * x2 * x;
            u = 1.f - 21.f * x5 + 35.f * x5 * x - 15.f * x5 * x2;
        }
        float pref = 0.6324555320336759f / len * u;
        float theta = PI * x;
        float s1, c1;
        __sincosf(theta, &s1, &c1);
        float c2 = 2.f * c1;
        float sp_ = 0.f, sn = s1;
        float flux = 0.f;
        unsigned int pk[4];
        #pragma unroll
        for (int i = 0; i < 4; ++i) {
            float r0 = pref * sn;
            float n1 = c2 * sn - sp_; sp_ = sn; sn = n1;
            float r1 = pref * sn;
            n1 = c2 * sn - sp_; sp_ = sn; sn = n1;
            flux += r0 * fw[2*i] + r1 * fw[2*i+1];
            pk[i] = (unsigned int)f2bf(r0) | ((unsigned int)f2bf(r1) << 16);
        }
        int p = atomicAdd(&cur[r], 1);
        *(uint4*)&ef_bf[(size_t)p * NBES] = make_uint4(pk[0], pk[1], pk[2], pk[3]);
        snd_s[p] = s;
        rcv_s[p] = r;
        int g = r / ng;
        atomicAdd(&lpol[g*3+0], flux * dx);
        atomicAdd(&lpol[g*3+1], flux * dy);
        atomicAdd(&lpol[g*3+2], flux * dz);
    }
    __syncthreads();
    for (int i = tid; i < GG * 3; i += 256) polpart[blockIdx.x * (GG * 3) + i] = lpol[i];
}

// Radial MLP (both phases MFMA) + segmented scatter. Block-per-tile (blockIdx =
// sorted order = locality). Wave-private LDS, zero barriers, 8 waves/EU.
__global__ __launch_bounds__(256, 8) void edge_mlp_k(
    const unsigned short* __restrict__ ef_bf, const int* __restrict__ snd_s,
    const int* __restrict__ rcv_s,
    const unsigned short* __restrict__ w1bf, const float* __restrict__ b1,
    const unsigned short* __restrict__ w2bf, const float* __restrict__ scal,
    float* __restrict__ agg0, int layer, int E_)
{
    __shared__ __align__(16) char smem[4][4352];
    int t = threadIdx.x, w = t >> 6, lane = t & 63;
    int mrow = lane & 15, quad = lane >> 4;
    int ebase = (blockIdx.x * 4 + w) * 16;
    unsigned short* hw = (unsigned short*)smem[w];
    float* cw = (float*)smem[w];

    int sv = snd_s[ebase + mrow];
    int rv = rcv_s[ebase + mrow];

    const short8 z8 = {0,0,0,0,0,0,0,0};
    short8 b_ef = z8;
    if (quad == 0) b_ef = *(const short8*)&ef_bf[(size_t)(ebase + mrow) * NBES];
    else if (quad == 1) b_ef[0] = (short)0x3F80;     // bf16(1.0) bias slot
    short8 a1f[4];
    #pragma unroll
    for (int nt = 0; nt < 4; ++nt) {
        a1f[nt] = z8;
        if (quad == 0) a1f[nt] = *(const short8*)&w1bf[layer * 512 + (nt * 16 + mrow) * 8];
        else if (quad == 1) a1f[nt][0] = (short)f2bf(b1[layer * FD + nt * 16 + mrow]);
    }
    const unsigned short* wb = w2bf + layer * 4096;
    short8 bf0[4], bf1[4];
    #pragma unroll
    for (int nt = 0; nt < 4; ++nt) {
        bf0[nt] = *(const short8*)&wb[(nt * 16 + mrow) * 64 + quad * 8];
        bf1[nt] = *(const short8*)&wb[(nt * 16 + mrow) * 64 + 32 + quad * 8];
    }

    // phase 1: h^T = [W1^T|b1] @ [ef|1]^T  (4 MFMAs), silu, pack bf16 -> hw
    f32x4 zf = {0.f, 0.f, 0.f, 0.f};
    #pragma unroll
    for (int nt = 0; nt < 4; ++nt) {
        f32x4 c1 = __builtin_amdgcn_mfma_f32_16x16x32_bf16(a1f[nt], b_ef, zf, 0, 0, 0);
        unsigned int p01 = (unsigned int)f2bf(silu(c1[0])) | ((unsigned int)f2bf(silu(c1[1])) << 16);
        unsigned int p23 = (unsigned int)f2bf(silu(c1[2])) | ((unsigned int)f2bf(silu(c1[3])) << 16);
        *(uint2*)&hw[mrow * 72 + nt * 16 + quad * 4] = make_uint2(p01, p23);
    }

    // phase 2: A = h @ W2 (8 MFMAs)
    short8 a0  = *(const short8*)&hw[mrow * 72 + quad * 8];
    short8 a1b = *(const short8*)&hw[mrow * 72 + 32 + quad * 8];
    f32x4 c[4];
    #pragma unroll
    for (int nt = 0; nt < 4; ++nt) {
        f32x4 cc = __builtin_amdgcn_mfma_f32_16x16x32_bf16(a0, bf0[nt], zf, 0, 0, 0);
        cc = __builtin_amdgcn_mfma_f32_16x16x32_bf16(a1b, bf1[nt], cc, 0, 0, 0);
        c[nt] = cc;
    }
    #pragma unroll
    for (int nt = 0; nt < 4; ++nt)
        #pragma unroll
        for (int reg = 0; reg < 4; ++reg)
            cw[(quad * 4 + reg) * 68 + nt * 16 + mrow] = c[nt][reg];

    // epilogue: batched loads (no control flow between issues), then segmented reduce
    int curR = __builtin_amdgcn_readlane(rv, 0);
    float run = 0.f;
    #pragma unroll
    for (int half = 0; half < 2; ++half) {
        float cv[8], sw[8];
        #pragma unroll
        for (int k = 0; k < 8; ++k) {
            int pp = half * 8 + k;
            cv[k] = cw[pp * 68 + lane];
            int s = __builtin_amdgcn_readlane(sv, pp);
            sw[k] = scal[(size_t)s * FD + lane];
        }
        #pragma unroll
        for (int k = 0; k < 8; ++k) {
            int pp = half * 8 + k;
            int r = __builtin_amdgcn_readlane(rv, pp);
            float v = cv[k] * sw[k];
            if (r != curR) {
                atomicAdd(&agg0[(size_t)curR * FD + lane], run);
                run = v; curR = r;
            } else {
                run += v;
            }
        }
    }
    atomicAdd(&agg0[(size_t)curR * FD + lane], run);
}

// Node update + block-level energy partial (nEpart[layer][block]).
__global__ __launch_bounds__(256) void node_update_k(
    float* __restrict__ scal, float* __restrict__ agg0,
    const int* __restrict__ spec, const float* __restrict__ prod_w,
    const float* __restrict__ readout_w, const float* __restrict__ ro2_w1,
    const float* __restrict__ ro2_b1, const float* __restrict__ ro2_w2,
    const float* __restrict__ charge_w, float* __restrict__ q,
    float* __restrict__ out_nodeE, float* __restrict__ nEpart,
    int layer, int last, int N_)
{
    __shared__ float vsh[4][FD];
    __shared__ float red[4];
    int wid = threadIdx.x >> 6, lane = threadIdx.x & 63;
    int n = blockIdx.x * 4 + wid;
    int sp = spec[n];
    size_t idx = (size_t)n * FD + lane;
    float a = agg0[idx] * 0.0625f;
    agg0[idx] = 0.f;
    float v = a + a * a + scal[idx] * prod_w[(layer * NEL + sp) * FD + lane];
    scal[idx] = v;

    float ne;
    if (!last) {
        ne = wred(v * readout_w[layer * FD + lane]);
    } else {
        vsh[wid][lane] = v;                    // wave-private, in-order DS
        float h = 0.f;
        if (lane < HML) {
            h = ro2_b1[lane];
            for (int ff = 0; ff < FD; ++ff) h += vsh[wid][ff] * ro2_w1[ff * HML + lane];
            h = silu(h) * ro2_w2[lane];
        }
        ne = wred(h);
    }
    float qs = wred(v * charge_w[layer * FD + lane]);
    if (lane == 0) {
        out_nodeE[n] += ne;
        q[n] += qs;
        red[wid] = ne;
    }
    __syncthreads();
    if (threadIdx.x == 0) nEpart[layer * NUB + blockIdx.x] = red[0] + red[1] + red[2] + red[3];
}

// Coulomb via triangular 64x64 chunk pairs (136/graph) + 1 reduce block/graph.
__global__ __launch_bounds__(256) void coulomb_final_k(
    const float* __restrict__ q, const float* __restrict__ pos,
    const int* __restrict__ spec, const float* __restrict__ ae,
    const float* __restrict__ fc, const float* __restrict__ nEpart,
    const float* __restrict__ polpart, float* __restrict__ out,
    int N_, int ng)
{
    __shared__ float sh[260];
    int vb = blockIdx.x;
    int g = vb / 137, rem = vb % 137;
    int t = threadIdx.x, lane = t & 63, w = t >> 6;

    if (rem < 136) {
        int a = 0, r2 = rem;
        while (r2 >= 16 - a) { r2 -= 16 - a; ++a; }
        int b = a + r2;
        const float* qg = q + (size_t)g * ng;
        const float* pg = pos + (size_t)g * ng * 3;
        float* qs_ = sh; float* jx = sh + 64; float* jy = sh + 128; float* jz = sh + 192;
        if (t < 64) {
            int j = b * 64 + t;
            bool ok = j < ng;
            qs_[t] = ok ? qg[j] : 0.f;
            jx[t] = ok ? pg[(size_t)j*3+0] : 0.f;
            jy[t] = ok ? pg[(size_t)j*3+1] : 0.f;
            jz[t] = ok ? pg[(size_t)j*3+2] : 0.f;
        }
        __syncthreads();
        int i = a * 64 + lane;
        float accu = 0.f;
        if (i < ng) {
            float qi = qg[i];
            float xi = pg[(size_t)i*3+0], yi = pg[(size_t)i*3+1], zi = pg[(size_t)i*3+2];
            #pragma unroll 4
            for (int k = 0; k < 16; ++k) {
                int jj = w * 16 + k;                  // wave-uniform -> LDS broadcast
                int j = b * 64 + jj;
                float dx = xi - jx[jj], dy = yi - jy[jj], dz = zi - jz[jj];
                float d2 = dx*dx + dy*dy + dz*dz + 1e-12f;
                float rinv = __frsqrt_rn(d2);
                float r = d2 * rinv;
                float x = 0.5f * r;
                float tt = __frcp_rn(1.f + 0.3275911f * x);
                float poly = ((((1.061405429f*tt - 1.453152027f)*tt + 1.421413741f)*tt
                               - 0.284496736f)*tt + 0.254829592f)*tt;
                float erfv = 1.f - poly * __expf(-x * x);
                float kern = (j == i) ? 0.f : erfv * rinv;
                accu += qi * qs_[jj] * kern;
            }
        }
        accu = wred(accu);
        if (lane == 0) sh[256 + w] = accu;
        __syncthreads();
        if (t == 0) {
            float s = sh[256] + sh[257] + sh[258] + sh[259];
            atomicAdd(&out[g], (a == b) ? 0.5f * s : s);
        }
    } else {
        float se0 = 0.f, sq = 0.f, p0 = 0.f, p1 = 0.f, p2 = 0.f, s0 = 0.f, s1 = 0.f;
        for (int n = g * ng + t; n < (g + 1) * ng; n += 256) {
            int sp = spec[n];
            float fq = fc[sp];
            se0 += ae[sp];
            sq += q[n];
            p0 += fq * pos[(size_t)n*3+0];
            p1 += fq * pos[(size_t)n*3+1];
            p2 += fq * pos[(size_t)n*3+2];
        }
        if (t < 250) {
            int b = g * 250 + t;
            s0 = nEpart[b];
            s1 = nEpart[NUB + b];
        }
        for (int b = t; b < EGB; b += 256) {
            p0 += polpart[b * (GG * 3) + g * 3 + 0];
            p1 += polpart[b * (GG * 3) + g * 3 + 1];
            p2 += polpart[b * (GG * 3) + g * 3 + 2];
        }
        float vals[7] = {se0, s0, s1, sq, p0, p1, p2};
        float* red = sh;
        #pragma unroll
        for (int k = 0; k < 7; ++k) {
            float r = wred(vals[k]);
            if (lane == 0) red[w * 8 + k] = r;
        }
        __syncthreads();
        if (t < 7) sh[64 + t] = red[t] + red[8 + t] + red[16 + t] + red[24 + t];
        __syncthreads();
        if (t == 0) {
            float a0 = sh[64], a1 = sh[65], a2 = sh[66];
            atomicAdd(&out[g], a0 + a1 + a2);
            float* contrib = out + GG + N_;
            contrib[g*3+0] = a0; contrib[g*3+1] = a1; contrib[g*3+2] = a2;
            float* pol = contrib + GG * 3;
            pol[g*3+0] = sh[68]; pol[g*3+1] = sh[69]; pol[g*3+2] = sh[70];
            float* qt = pol + GG * 3;
            qt[g] = sh[67];
        }
    }
}

extern "C" void kernel_launch(void* const* d_in, const int* in_sizes, int n_in,
                              void* d_out, int out_size, void* d_ws, size_t ws_size,
                              hipStream_t stream)
{
    const float* node_attrs      = (const float*)d_in[0];
    const float* positions       = (const float*)d_in[1];
    const int*   edge_index      = (const int*)d_in[2];
    const float* atomic_energies = (const float*)d_in[5];
    const float* embed_w         = (const float*)d_in[6];
    const float* radial_w1       = (const float*)d_in[7];
    const float* radial_b1       = (const float*)d_in[8];
    const float* radial_w2       = (const float*)d_in[9];
    const float* prod_w          = (const float*)d_in[10];
    const float* readout_w       = (const float*)d_in[11];
    const float* ro2_w1          = (const float*)d_in[12];
    const float* ro2_b1          = (const float*)d_in[13];
    const float* ro2_w2          = (const float*)d_in[14];
    const float* charge_w        = (const float*)d_in[15];
    const float* flux_w          = (const float*)d_in[16];
    const float* formal_charges  = (const float*)d_in[17];

    int N = in_sizes[0] / NEL;     // 20000
    int E = in_sizes[2] / 2;       // 320000
    int ng = N / GG;               // 1000

    float* ws      = (float*)d_ws;
    float* scal    = ws;                                   // [N,64]
    float* agg0    = scal + (size_t)N * FD;                // [N,64]
    unsigned short* ef_bf = (unsigned short*)(agg0 + (size_t)N * FD); // [E,8] bf16 sorted
    float* q       = (float*)(ef_bf + (size_t)E * NBES);   // [N]
    int*   spec    = (int*)(q + N);                        // [N]
    float* nEpart  = (float*)(spec + N);                   // [2*NUB]
    float* polpart = nEpart + 2 * NUB;                     // [EGB*60]
    int*   cnt     = (int*)(polpart + EGB * (GG * 3));     // [N]  (memset)
    int*   cur     = cnt + N;                              // [N]
    int*   snd_s   = cur + N;                              // [E]
    int*   rcv_s   = snd_s + E;                            // [E]
    unsigned short* w2bf = (unsigned short*)(rcv_s + E);   // [2*4096]
    unsigned short* w1bf = w2bf + 8192;                    // [2*512]

    float* out = (float*)d_out;
    float* out_nodeE = out + GG;

    hipMemsetAsync(cnt, 0, (size_t)N * sizeof(int), stream);

    setup_k<<<(N * FD) / 256, 256, 0, stream>>>(
        node_attrs, atomic_energies, formal_charges, embed_w, edge_index,
        spec, q, out, scal, agg0, cnt, N, E);
    scan_k<<<1, 1024, 0, stream>>>(cnt, cur, radial_w1, radial_w2, w1bf, w2bf, N);
    geom_scatter_k<<<EGB, 256, 0, stream>>>(
        positions, edge_index, flux_w, cur, snd_s, rcv_s, ef_bf, polpart, E, ng);

    for (int l = 0; l < 2; ++l) {
        edge_mlp_k<<<E / 64, 256, 0, stream>>>(
            ef_bf, snd_s, rcv_s, w1bf, radial_b1, w2bf, scal, agg0, l, E);
        node_update_k<<<N / 4, 256, 0, stream>>>(
            scal, agg0, spec, prod_w, readout_w, ro2_w1, ro2_b1, ro2_w2,
            charge_w, q, out_nodeE, nEpart, l, (l == 1) ? 1 : 0, N);
    }

    coulomb_final_k<<<GG * 137, 256, 0, stream>>>(
        q, positions, spec, atomic_energies, formal_charges,
        nEpart, polpart, out, N, ng);
}